// Round 2
// baseline (120.113 us; speedup 1.0000x reference)
//
#include <hip/hip_runtime.h>
#include <math.h>

#define DEV __device__ __forceinline__

DEV float gelu_exact(float x) {
    return 0.5f * x * (1.0f + erff(x * 0.70710678118654752f));
}

// ---------------- K1: adjacency bitmask ----------------
// grid = 500 blocks (one per row i), block = 512 threads, lane j.
__global__ __launch_bounds__(512)
void mask_kernel(const float* __restrict__ emb,
                 unsigned long long* __restrict__ maskw) {
    const int i = blockIdx.x;
    const int j = threadIdx.x;
    float ei[8], ej[8];
    float si = 0.f, sj = 0.f;
#pragma unroll
    for (int e = 0; e < 8; ++e) { ei[e] = emb[i * 8 + e]; si += ei[e] * ei[e]; }
    const int jj = (j < 500) ? j : 0;
#pragma unroll
    for (int e = 0; e < 8; ++e) { ej[e] = emb[jj * 8 + e]; sj += ej[e] * ej[e]; }
    const float ri = 1.0f / sqrtf(si);
    const float rj = 1.0f / sqrtf(sj);
    float dot = 0.f;
#pragma unroll
    for (int e = 0; e < 8; ++e) dot += (ei[e] * ri) * (ej[e] * rj);
    const bool pred = (j < 500) && (dot > 0.5f);
    unsigned long long m = __ballot(pred);
    if ((threadIdx.x & 63) == 0) maskw[i * 8 + (threadIdx.x >> 6)] = m;
}

// ---------------- K2: fused 2-layer GAT, one block per graph ----------------
// grid = 96 blocks, 512 threads. LDS regions (64000 B total):
//   region0 floats [0,4000):      xh  [500][8]  (layer-1 input) / xh2 (layer-2 input)
//   region1 floats [4000,12000):  h1s [500][8] + ss1[4*500] + sd1[4*500]  / h2 [500][16]
//   region2 floats [12000,16000): ss2[4*500] + sd2[4*500]
__global__ __launch_bounds__(512)
void gat_both_kernel(const float* __restrict__ x,    // [96,500,3]
                     const float* __restrict__ pw,   // [3,8]
                     const float* __restrict__ pb,   // [8]
                     const float* __restrict__ w1,   // [8,4,2]
                     const float* __restrict__ a1s,  // [4,2]
                     const float* __restrict__ a1d,  // [4,2]
                     const float* __restrict__ b1,   // [8]
                     const float* __restrict__ w2,   // [8,4,4]
                     const float* __restrict__ a2s,  // [4,4]
                     const float* __restrict__ a2d,  // [4,4]
                     const float* __restrict__ b2,   // [16]
                     const unsigned long long* __restrict__ maskw, // [500][8]
                     float* __restrict__ out) {      // [96,500,16]
    const int b = blockIdx.x;
    const int tid = threadIdx.x;
    __shared__ float lds[16000];
    float* xh  = lds;           // 4000
    float* h1s = lds + 4000;    // 4000
    float* ss1 = lds + 8000;    // 2000
    float* sd1 = lds + 10000;   // 2000
    float* h2  = lds + 4000;    // 8000 (aliases h1s/ss1/sd1)
    float* ss2 = lds + 12000;   // 2000
    float* sd2 = lds + 14000;   // 2000

    // A: input projection -> xh
    for (int n = tid; n < 500; n += 512) {
        const float* xr = x + ((size_t)b * 500 + n) * 3;
        const float x0 = xr[0], x1 = xr[1], x2 = xr[2];
#pragma unroll
        for (int e = 0; e < 8; ++e)
            xh[n * 8 + e] = x0 * pw[e] + x1 * pw[8 + e] + x2 * pw[16 + e] + pb[e];
    }
    __syncthreads();

    // B: layer-1 per-head projection + attention logits
    for (int n = tid; n < 500; n += 512) {
        float xv[8];
#pragma unroll
        for (int e = 0; e < 8; ++e) xv[e] = xh[n * 8 + e];
#pragma unroll
        for (int h = 0; h < 4; ++h) {
            float a0 = 0.f, a1 = 0.f;
#pragma unroll
            for (int e = 0; e < 8; ++e) {
                a0 += xv[e] * w1[(e * 4 + h) * 2 + 0];
                a1 += xv[e] * w1[(e * 4 + h) * 2 + 1];
            }
            h1s[n * 8 + h * 2 + 0] = a0;
            h1s[n * 8 + h * 2 + 1] = a1;
            ss1[h * 500 + n] = a0 * a1s[h * 2] + a1 * a1s[h * 2 + 1];
            sd1[h * 500 + n] = a0 * a1d[h * 2] + a1 * a1d[h * 2 + 1];
        }
    }
    __syncthreads();

    // C: layer-1 masked softmax aggregation + bias + GELU -> xh2 (region0)
    for (int item = tid; item < 2000; item += 512) {
        const int h = item / 500, i = item - h * 500;
        const float dd = sd1[h * 500 + i];
        float n0 = 0.f, n1 = 0.f, den = 0.f;
#pragma unroll 1
        for (int wi = 0; wi < 8; ++wi) {
            unsigned long long m = maskw[i * 8 + wi];
            while (m) {
                const int bit = __ffsll(m) - 1;
                m &= (m - 1);
                const int j = wi * 64 + bit;
                float e = dd + ss1[h * 500 + j];
                e = (e > 0.f) ? e : 0.2f * e;
                const float w = __expf(e);
                den += w;
                n0 += w * h1s[j * 8 + h * 2 + 0];
                n1 += w * h1s[j * 8 + h * 2 + 1];
            }
        }
        const float inv = 1.0f / den;  // self-loop guarantees den > 0
        xh[i * 8 + h * 2 + 0] = gelu_exact(n0 * inv + b1[h * 2 + 0]);
        xh[i * 8 + h * 2 + 1] = gelu_exact(n1 * inv + b1[h * 2 + 1]);
    }
    __syncthreads();

    // D: layer-2 per-head projection + logits (h2 overwrites region1)
    for (int n = tid; n < 500; n += 512) {
        float xv[8];
#pragma unroll
        for (int e = 0; e < 8; ++e) xv[e] = xh[n * 8 + e];
#pragma unroll
        for (int h = 0; h < 4; ++h) {
            float acc[4] = {0.f, 0.f, 0.f, 0.f};
#pragma unroll
            for (int e = 0; e < 8; ++e) {
                const float xe = xv[e];
#pragma unroll
                for (int c = 0; c < 4; ++c) acc[c] += xe * w2[(e * 4 + h) * 4 + c];
            }
            float ss = 0.f, sd = 0.f;
#pragma unroll
            for (int c = 0; c < 4; ++c) {
                h2[n * 16 + h * 4 + c] = acc[c];
                ss += acc[c] * a2s[h * 4 + c];
                sd += acc[c] * a2d[h * 4 + c];
            }
            ss2[h * 500 + n] = ss;
            sd2[h * 500 + n] = sd;
        }
    }
    __syncthreads();

    // E: layer-2 masked softmax aggregation + bias -> global
    for (int item = tid; item < 2000; item += 512) {
        const int h = item / 500, i = item - h * 500;
        const float dd = sd2[h * 500 + i];
        float num[4] = {0.f, 0.f, 0.f, 0.f};
        float den = 0.f;
#pragma unroll 1
        for (int wi = 0; wi < 8; ++wi) {
            unsigned long long m = maskw[i * 8 + wi];
            while (m) {
                const int bit = __ffsll(m) - 1;
                m &= (m - 1);
                const int j = wi * 64 + bit;
                float e = dd + ss2[h * 500 + j];
                e = (e > 0.f) ? e : 0.2f * e;
                const float w = __expf(e);
                den += w;
#pragma unroll
                for (int c = 0; c < 4; ++c) num[c] += w * h2[j * 16 + h * 4 + c];
            }
        }
        const float inv = 1.0f / den;
        float* orow = out + ((size_t)b * 500 + i) * 16 + h * 4;
#pragma unroll
        for (int c = 0; c < 4; ++c) orow[c] = num[c] * inv + b2[h * 4 + c];
    }
}

// ---------------- K3: transformer + pool + regressor ----------------
// grid = 2000 sequences, block = 64 threads (1 wave).
// Work distribution: idx phases map lane -> (s = it*4 + lane/16, d = lane%16);
// LayerNorm is done with shfl_xor reductions inside each 16-lane group.
__global__ __launch_bounds__(64)
void transformer_kernel(const float* __restrict__ tin,  // [2000,24,16]
                        const float* __restrict__ wq, const float* __restrict__ bq,
                        const float* __restrict__ wk, const float* __restrict__ bk,
                        const float* __restrict__ wv, const float* __restrict__ bv,
                        const float* __restrict__ wo, const float* __restrict__ bo,
                        const float* __restrict__ ln1g, const float* __restrict__ ln1b,
                        const float* __restrict__ ln2g, const float* __restrict__ ln2b,
                        const float* __restrict__ fw1, const float* __restrict__ fb1,
                        const float* __restrict__ fw2, const float* __restrict__ fb2,
                        const float* __restrict__ rw1, const float* __restrict__ rb1,
                        const float* __restrict__ rw2, const float* __restrict__ rb2,
                        float* __restrict__ outp) {
    const int r = blockIdx.x;
    const int lane = threadIdx.x;
    const int d = lane & 15;
    const int srow = lane >> 4;  // 0..3
    __shared__ float t0[24][16], qs[24][16], ks[24][16], vs[24][16];
    __shared__ float os[24][16], t1[24][16], hid[24][32], pooled[16];

    const float* row = tin + (size_t)r * 384;
#pragma unroll
    for (int it = 0; it < 6; ++it) {
        const int idx = it * 64 + lane;
        t0[idx >> 4][idx & 15] = row[idx];
    }
    __syncthreads();

    // QKV
#pragma unroll
    for (int it = 0; it < 6; ++it) {
        const int s = it * 4 + srow;
        float aq = bq[d], ak = bk[d], av = bv[d];
#pragma unroll
        for (int e = 0; e < 16; ++e) {
            const float tv = t0[s][e];
            aq += tv * wq[e * 16 + d];
            ak += tv * wk[e * 16 + d];
            av += tv * wv[e * 16 + d];
        }
        qs[s][d] = aq; ks[s][d] = ak; vs[s][d] = av;
    }
    __syncthreads();

    // attention: lane = h*24 + s for lane < 48
    if (lane < 48) {
        const int h = lane / 24, s = lane % 24;
        float sc[24];
        float mx = -1e30f;
#pragma unroll
        for (int t = 0; t < 24; ++t) {
            float a = 0.f;
#pragma unroll
            for (int d2 = 0; d2 < 8; ++d2) a += qs[s][h * 8 + d2] * ks[t][h * 8 + d2];
            a *= 0.35355339059327373f;  // 1/sqrt(8)
            sc[t] = a;
            mx = fmaxf(mx, a);
        }
        float sum = 0.f;
#pragma unroll
        for (int t = 0; t < 24; ++t) { sc[t] = __expf(sc[t] - mx); sum += sc[t]; }
        const float inv = 1.0f / sum;
#pragma unroll
        for (int d2 = 0; d2 < 8; ++d2) {
            float acc = 0.f;
#pragma unroll
            for (int t = 0; t < 24; ++t) acc += sc[t] * vs[t][h * 8 + d2];
            os[s][h * 8 + d2] = acc * inv;
        }
    }
    __syncthreads();

    // out-proj + residual + LN1 (shuffle LN within 16-lane groups)
#pragma unroll
    for (int it = 0; it < 6; ++it) {
        const int s = it * 4 + srow;
        float a = bo[d];
#pragma unroll
        for (int hd = 0; hd < 16; ++hd) a += os[s][hd] * wo[hd * 16 + d];
        float xv = t0[s][d] + a;
        float sum = xv;
        sum += __shfl_xor(sum, 1); sum += __shfl_xor(sum, 2);
        sum += __shfl_xor(sum, 4); sum += __shfl_xor(sum, 8);
        const float mean = sum * 0.0625f;
        const float df = xv - mean;
        float v2 = df * df;
        v2 += __shfl_xor(v2, 1); v2 += __shfl_xor(v2, 2);
        v2 += __shfl_xor(v2, 4); v2 += __shfl_xor(v2, 8);
        const float var = v2 * 0.0625f;
        t1[s][d] = df * rsqrtf(var + 1e-3f) * ln1g[d] + ln1b[d];
    }
    __syncthreads();

    // FFN hidden [24][32]
#pragma unroll
    for (int it = 0; it < 12; ++it) {
        const int idx = it * 64 + lane;
        const int s = idx >> 5, f = idx & 31;
        float a = fb1[f];
#pragma unroll
        for (int e = 0; e < 16; ++e) a += t1[s][e] * fw1[e * 32 + f];
        hid[s][f] = gelu_exact(a);
    }
    __syncthreads();

    // FFN out + residual + LN2 (shuffle LN) + fused mean-pool accumulate
    float pacc = 0.f;
#pragma unroll
    for (int it = 0; it < 6; ++it) {
        const int s = it * 4 + srow;
        float a = fb2[d];
#pragma unroll
        for (int f = 0; f < 32; ++f) a += hid[s][f] * fw2[f * 16 + d];
        float xv = t1[s][d] + a;
        float sum = xv;
        sum += __shfl_xor(sum, 1); sum += __shfl_xor(sum, 2);
        sum += __shfl_xor(sum, 4); sum += __shfl_xor(sum, 8);
        const float mean = sum * 0.0625f;
        const float df = xv - mean;
        float v2 = df * df;
        v2 += __shfl_xor(v2, 1); v2 += __shfl_xor(v2, 2);
        v2 += __shfl_xor(v2, 4); v2 += __shfl_xor(v2, 8);
        const float var = v2 * 0.0625f;
        pacc += df * rsqrtf(var + 1e-3f) * ln2g[d] + ln2b[d];
    }
    // reduce pooled sum across the 4 row-groups (lanes sharing d)
    pacc += __shfl_xor(pacc, 16);
    pacc += __shfl_xor(pacc, 32);
    if (lane < 16) pooled[lane] = pacc * (1.0f / 24.0f);
    __syncthreads();

    // regressor: gelu(pooled @ rw1 + rb1) @ rw2 + rb2
    float partial = 0.f;
    if (lane < 16) {
        float a = rb1[lane];
#pragma unroll
        for (int e = 0; e < 16; ++e) a += pooled[e] * rw1[e * 16 + lane];
        partial = gelu_exact(a) * rw2[lane];
    }
    partial += __shfl_xor(partial, 8);
    partial += __shfl_xor(partial, 4);
    partial += __shfl_xor(partial, 2);
    partial += __shfl_xor(partial, 1);
    if (lane == 0) outp[r] = partial + rb2[0];
}

extern "C" void kernel_launch(void* const* d_in, const int* in_sizes, int n_in,
                              void* d_out, int out_size, void* d_ws, size_t ws_size,
                              hipStream_t stream) {
    const float* x      = (const float*)d_in[0];
    const float* emb    = (const float*)d_in[1];
    const float* proj_w = (const float*)d_in[2];
    const float* proj_b = (const float*)d_in[3];
    const float* g1_w   = (const float*)d_in[4];
    const float* g1_as  = (const float*)d_in[5];
    const float* g1_ad  = (const float*)d_in[6];
    const float* g1_b   = (const float*)d_in[7];
    const float* g2_w   = (const float*)d_in[8];
    const float* g2_as  = (const float*)d_in[9];
    const float* g2_ad  = (const float*)d_in[10];
    const float* g2_b   = (const float*)d_in[11];
    const float* wq = (const float*)d_in[12];
    const float* bq = (const float*)d_in[13];
    const float* wk = (const float*)d_in[14];
    const float* bk = (const float*)d_in[15];
    const float* wv = (const float*)d_in[16];
    const float* bv = (const float*)d_in[17];
    const float* wo = (const float*)d_in[18];
    const float* bo = (const float*)d_in[19];
    const float* ln1g = (const float*)d_in[20];
    const float* ln1b = (const float*)d_in[21];
    const float* ln2g = (const float*)d_in[22];
    const float* ln2b = (const float*)d_in[23];
    const float* fw1 = (const float*)d_in[24];
    const float* fb1 = (const float*)d_in[25];
    const float* fw2 = (const float*)d_in[26];
    const float* fb2 = (const float*)d_in[27];
    const float* rw1 = (const float*)d_in[28];
    const float* rb1 = (const float*)d_in[29];
    const float* rw2 = (const float*)d_in[30];
    const float* rb2 = (const float*)d_in[31];

    // workspace layout
    unsigned long long* maskw = (unsigned long long*)d_ws;   // 32000 B (pad to 32768)
    float* t_buf = (float*)((char*)d_ws + 32768);            // 96*500*16*4 = 3,072,000 B

    mask_kernel<<<500, 512, 0, stream>>>(emb, maskw);
    gat_both_kernel<<<96, 512, 0, stream>>>(
        x, proj_w, proj_b, g1_w, g1_as, g1_ad, g1_b,
        g2_w, g2_as, g2_ad, g2_b, maskw, t_buf);
    transformer_kernel<<<2000, 64, 0, stream>>>(
        t_buf, wq, bq, wk, bk, wv, bv, wo, bo, ln1g, ln1b, ln2g, ln2b,
        fw1, fb1, fw2, fb2, rw1, rb1, rw2, rb2, (float*)d_out);
}

// Round 3
// 76.476 us; speedup vs baseline: 1.5706x; 1.5706x over previous
//
#include <hip/hip_runtime.h>
#include <math.h>

#define DEV __device__ __forceinline__

DEV float gelu_exact(float x) {
    return 0.5f * x * (1.0f + erff(x * 0.70710678118654752f));
}

// ---------------- K1: adjacency bitmask ----------------
// grid = 500 blocks (one per row i), block = 512 threads, lane j.
__global__ __launch_bounds__(512)
void mask_kernel(const float* __restrict__ emb,
                 unsigned long long* __restrict__ maskw) {
    const int i = blockIdx.x;
    const int j = threadIdx.x;
    float ei[8], ej[8];
    float si = 0.f, sj = 0.f;
#pragma unroll
    for (int e = 0; e < 8; ++e) { ei[e] = emb[i * 8 + e]; si += ei[e] * ei[e]; }
    const int jj = (j < 500) ? j : 0;
#pragma unroll
    for (int e = 0; e < 8; ++e) { ej[e] = emb[jj * 8 + e]; sj += ej[e] * ej[e]; }
    const float ri = 1.0f / sqrtf(si);
    const float rj = 1.0f / sqrtf(sj);
    float dot = 0.f;
#pragma unroll
    for (int e = 0; e < 8; ++e) dot += (ei[e] * ri) * (ej[e] * rj);
    const bool pred = (j < 500) && (dot > 0.5f);
    unsigned long long m = __ballot(pred);
    if ((threadIdx.x & 63) == 0) maskw[i * 8 + (threadIdx.x >> 6)] = m;
}

// ---------------- K2/K3: per-layer GAT ----------------
// grid = 96 graphs * 4 heads = 384 blocks, block = 512 threads (1 row/thread).
// LDS strides odd (9 and C+1) so random-j reads in the bit-scan hit all banks.
template <int C, int OUTS, bool PROJ, bool GELU_OUT>
__global__ __launch_bounds__(512)
void gat_kernel(const float* __restrict__ in,   // PROJ ? [96,500,3] : [96,500,8]
                const float* __restrict__ pw,   // [3,8] (PROJ only)
                const float* __restrict__ pb,   // [8]
                const float* __restrict__ W,    // [8,4,C]
                const float* __restrict__ asrc, // [4,C]
                const float* __restrict__ adst, // [4,C]
                const float* __restrict__ bias, // [4*C]
                const unsigned long long* __restrict__ maskw, // [500][8]
                float* __restrict__ out) {      // [96,500,OUTS], write head*C..head*C+C
    constexpr int HS = C + 1;                   // h1 stride (3 or 5, odd)
    const int b = blockIdx.x >> 2;
    const int head = blockIdx.x & 3;
    const int tid = threadIdx.x;
    __shared__ float xh[500 * 9];
    __shared__ float h1[500 * HS];
    __shared__ float ssrc[500];
    __shared__ float sdst[500];

    // A: stage input (optionally fused dense proj 3->8)
    if (tid < 500) {
        if constexpr (PROJ) {
            const float* xr = in + ((size_t)b * 500 + tid) * 3;
            const float x0 = xr[0], x1 = xr[1], x2 = xr[2];
#pragma unroll
            for (int e = 0; e < 8; ++e)
                xh[tid * 9 + e] = x0 * pw[e] + x1 * pw[8 + e] + x2 * pw[16 + e] + pb[e];
        } else {
            const float4* xr = (const float4*)(in + ((size_t)b * 500 + tid) * 8);
            const float4 v0 = xr[0], v1 = xr[1];
            xh[tid * 9 + 0] = v0.x; xh[tid * 9 + 1] = v0.y;
            xh[tid * 9 + 2] = v0.z; xh[tid * 9 + 3] = v0.w;
            xh[tid * 9 + 4] = v1.x; xh[tid * 9 + 5] = v1.y;
            xh[tid * 9 + 6] = v1.z; xh[tid * 9 + 7] = v1.w;
        }
    }
    __syncthreads();

    // B: per-head projection + attention logits (weights uniform -> scalar loads)
    if (tid < 500) {
        float xv[8];
#pragma unroll
        for (int e = 0; e < 8; ++e) xv[e] = xh[tid * 9 + e];
        float acc[C];
#pragma unroll
        for (int c = 0; c < C; ++c) acc[c] = 0.f;
#pragma unroll
        for (int e = 0; e < 8; ++e) {
            const float xe = xv[e];
#pragma unroll
            for (int c = 0; c < C; ++c) acc[c] += xe * W[(e * 4 + head) * C + c];
        }
        float ss = 0.f, sd = 0.f;
#pragma unroll
        for (int c = 0; c < C; ++c) {
            h1[tid * HS + c] = acc[c];
            ss += acc[c] * asrc[head * C + c];
            sd += acc[c] * adst[head * C + c];
        }
        ssrc[tid] = ss;
        sdst[tid] = sd;
    }
    __syncthreads();

    // C: masked rank-1 softmax aggregation (bit-scan over sparse neighbors)
    if (tid < 500) {
        const int i = tid;
        const float dd = sdst[i];
        float num[C];
#pragma unroll
        for (int c = 0; c < C; ++c) num[c] = 0.f;
        float den = 0.f;
#pragma unroll 1
        for (int wi = 0; wi < 8; ++wi) {
            unsigned long long m = maskw[i * 8 + wi];
            while (m) {
                const int bit = __ffsll(m) - 1;
                m &= (m - 1);
                const int j = wi * 64 + bit;
                float e = dd + ssrc[j];
                e = (e > 0.f) ? e : 0.2f * e;
                const float w = __expf(e);
                den += w;
#pragma unroll
                for (int c = 0; c < C; ++c) num[c] += w * h1[j * HS + c];
            }
        }
        const float inv = 1.0f / den;  // diag self-loop guarantees den > 0
        float* orow = out + ((size_t)b * 500 + i) * OUTS + head * C;
#pragma unroll
        for (int c = 0; c < C; ++c) {
            float v = num[c] * inv + bias[head * C + c];
            if constexpr (GELU_OUT) v = gelu_exact(v);
            orow[c] = v;
        }
    }
}

// ---------------- K4: transformer + pool + regressor ----------------
// grid = 2000 sequences, block = 64 threads (1 wave).
__global__ __launch_bounds__(64)
void transformer_kernel(const float* __restrict__ tin,  // [2000,24,16]
                        const float* __restrict__ wq, const float* __restrict__ bq,
                        const float* __restrict__ wk, const float* __restrict__ bk,
                        const float* __restrict__ wv, const float* __restrict__ bv,
                        const float* __restrict__ wo, const float* __restrict__ bo,
                        const float* __restrict__ ln1g, const float* __restrict__ ln1b,
                        const float* __restrict__ ln2g, const float* __restrict__ ln2b,
                        const float* __restrict__ fw1, const float* __restrict__ fb1,
                        const float* __restrict__ fw2, const float* __restrict__ fb2,
                        const float* __restrict__ rw1, const float* __restrict__ rb1,
                        const float* __restrict__ rw2, const float* __restrict__ rb2,
                        float* __restrict__ outp) {
    const int r = blockIdx.x;
    const int lane = threadIdx.x;
    const int d = lane & 15;
    const int srow = lane >> 4;  // 0..3
    __shared__ float t0[24][16], qs[24][16], ks[24][16], vs[24][16];
    __shared__ float os[24][16], t1[24][16], hid[24][32], pooled[16];

    const float* row = tin + (size_t)r * 384;
#pragma unroll
    for (int it = 0; it < 6; ++it) {
        const int idx = it * 64 + lane;
        t0[idx >> 4][idx & 15] = row[idx];
    }
    __syncthreads();

    // QKV
#pragma unroll
    for (int it = 0; it < 6; ++it) {
        const int s = it * 4 + srow;
        float aq = bq[d], ak = bk[d], av = bv[d];
#pragma unroll
        for (int e = 0; e < 16; ++e) {
            const float tv = t0[s][e];
            aq += tv * wq[e * 16 + d];
            ak += tv * wk[e * 16 + d];
            av += tv * wv[e * 16 + d];
        }
        qs[s][d] = aq; ks[s][d] = ak; vs[s][d] = av;
    }
    __syncthreads();

    // attention: lane = h*24 + s for lane < 48
    if (lane < 48) {
        const int h = lane / 24, s = lane % 24;
        float sc[24];
        float mx = -1e30f;
#pragma unroll
        for (int t = 0; t < 24; ++t) {
            float a = 0.f;
#pragma unroll
            for (int d2 = 0; d2 < 8; ++d2) a += qs[s][h * 8 + d2] * ks[t][h * 8 + d2];
            a *= 0.35355339059327373f;  // 1/sqrt(8)
            sc[t] = a;
            mx = fmaxf(mx, a);
        }
        float sum = 0.f;
#pragma unroll
        for (int t = 0; t < 24; ++t) { sc[t] = __expf(sc[t] - mx); sum += sc[t]; }
        const float inv = 1.0f / sum;
#pragma unroll
        for (int d2 = 0; d2 < 8; ++d2) {
            float acc = 0.f;
#pragma unroll
            for (int t = 0; t < 24; ++t) acc += sc[t] * vs[t][h * 8 + d2];
            os[s][h * 8 + d2] = acc * inv;
        }
    }
    __syncthreads();

    // out-proj + residual + LN1 (shuffle LN within 16-lane groups)
#pragma unroll
    for (int it = 0; it < 6; ++it) {
        const int s = it * 4 + srow;
        float a = bo[d];
#pragma unroll
        for (int hd = 0; hd < 16; ++hd) a += os[s][hd] * wo[hd * 16 + d];
        float xv = t0[s][d] + a;
        float sum = xv;
        sum += __shfl_xor(sum, 1); sum += __shfl_xor(sum, 2);
        sum += __shfl_xor(sum, 4); sum += __shfl_xor(sum, 8);
        const float mean = sum * 0.0625f;
        const float df = xv - mean;
        float v2 = df * df;
        v2 += __shfl_xor(v2, 1); v2 += __shfl_xor(v2, 2);
        v2 += __shfl_xor(v2, 4); v2 += __shfl_xor(v2, 8);
        const float var = v2 * 0.0625f;
        t1[s][d] = df * rsqrtf(var + 1e-3f) * ln1g[d] + ln1b[d];
    }
    __syncthreads();

    // FFN hidden [24][32]
#pragma unroll
    for (int it = 0; it < 12; ++it) {
        const int idx = it * 64 + lane;
        const int s = idx >> 5, f = idx & 31;
        float a = fb1[f];
#pragma unroll
        for (int e = 0; e < 16; ++e) a += t1[s][e] * fw1[e * 32 + f];
        hid[s][f] = gelu_exact(a);
    }
    __syncthreads();

    // FFN out + residual + LN2 (shuffle LN) + fused mean-pool accumulate
    float pacc = 0.f;
#pragma unroll
    for (int it = 0; it < 6; ++it) {
        const int s = it * 4 + srow;
        float a = fb2[d];
#pragma unroll
        for (int f = 0; f < 32; ++f) a += hid[s][f] * fw2[f * 16 + d];
        float xv = t1[s][d] + a;
        float sum = xv;
        sum += __shfl_xor(sum, 1); sum += __shfl_xor(sum, 2);
        sum += __shfl_xor(sum, 4); sum += __shfl_xor(sum, 8);
        const float mean = sum * 0.0625f;
        const float df = xv - mean;
        float v2 = df * df;
        v2 += __shfl_xor(v2, 1); v2 += __shfl_xor(v2, 2);
        v2 += __shfl_xor(v2, 4); v2 += __shfl_xor(v2, 8);
        const float var = v2 * 0.0625f;
        pacc += df * rsqrtf(var + 1e-3f) * ln2g[d] + ln2b[d];
    }
    // reduce pooled sum across the 4 row-groups (lanes sharing d)
    pacc += __shfl_xor(pacc, 16);
    pacc += __shfl_xor(pacc, 32);
    if (lane < 16) pooled[lane] = pacc * (1.0f / 24.0f);
    __syncthreads();

    // regressor: gelu(pooled @ rw1 + rb1) @ rw2 + rb2
    float partial = 0.f;
    if (lane < 16) {
        float a = rb1[lane];
#pragma unroll
        for (int e = 0; e < 16; ++e) a += pooled[e] * rw1[e * 16 + lane];
        partial = gelu_exact(a) * rw2[lane];
    }
    partial += __shfl_xor(partial, 8);
    partial += __shfl_xor(partial, 4);
    partial += __shfl_xor(partial, 2);
    partial += __shfl_xor(partial, 1);
    if (lane == 0) outp[r] = partial + rb2[0];
}

extern "C" void kernel_launch(void* const* d_in, const int* in_sizes, int n_in,
                              void* d_out, int out_size, void* d_ws, size_t ws_size,
                              hipStream_t stream) {
    const float* x      = (const float*)d_in[0];
    const float* emb    = (const float*)d_in[1];
    const float* proj_w = (const float*)d_in[2];
    const float* proj_b = (const float*)d_in[3];
    const float* g1_w   = (const float*)d_in[4];
    const float* g1_as  = (const float*)d_in[5];
    const float* g1_ad  = (const float*)d_in[6];
    const float* g1_b   = (const float*)d_in[7];
    const float* g2_w   = (const float*)d_in[8];
    const float* g2_as  = (const float*)d_in[9];
    const float* g2_ad  = (const float*)d_in[10];
    const float* g2_b   = (const float*)d_in[11];
    const float* wq = (const float*)d_in[12];
    const float* bq = (const float*)d_in[13];
    const float* wk = (const float*)d_in[14];
    const float* bk = (const float*)d_in[15];
    const float* wv = (const float*)d_in[16];
    const float* bv = (const float*)d_in[17];
    const float* wo = (const float*)d_in[18];
    const float* bo = (const float*)d_in[19];
    const float* ln1g = (const float*)d_in[20];
    const float* ln1b = (const float*)d_in[21];
    const float* ln2g = (const float*)d_in[22];
    const float* ln2b = (const float*)d_in[23];
    const float* fw1 = (const float*)d_in[24];
    const float* fb1 = (const float*)d_in[25];
    const float* fw2 = (const float*)d_in[26];
    const float* fb2 = (const float*)d_in[27];
    const float* rw1 = (const float*)d_in[28];
    const float* rb1 = (const float*)d_in[29];
    const float* rw2 = (const float*)d_in[30];
    const float* rb2 = (const float*)d_in[31];

    // workspace layout
    unsigned long long* maskw = (unsigned long long*)d_ws;   // 32000 B (pad to 32768)
    float* h_g1  = (float*)((char*)d_ws + 32768);            // 96*500*8*4  = 1,536,000 B
    float* t_buf = (float*)((char*)d_ws + 32768 + 1536000);  // 96*500*16*4 = 3,072,000 B

    mask_kernel<<<500, 512, 0, stream>>>(emb, maskw);
    gat_kernel<2, 8, true, true><<<384, 512, 0, stream>>>(
        x, proj_w, proj_b, g1_w, g1_as, g1_ad, g1_b, maskw, h_g1);
    gat_kernel<4, 16, false, false><<<384, 512, 0, stream>>>(
        h_g1, nullptr, nullptr, g2_w, g2_as, g2_ad, g2_b, maskw, t_buf);
    transformer_kernel<<<2000, 64, 0, stream>>>(
        t_buf, wq, bq, wk, bk, wv, bv, wo, bo, ln1g, ln1b, ln2g, ln2b,
        fw1, fb1, fw2, fb2, rw1, rb1, rw2, rb2, (float*)d_out);
}

// Round 4
// 61.178 us; speedup vs baseline: 1.9633x; 1.2501x over previous
//
#include <hip/hip_runtime.h>
#include <math.h>
#include <type_traits>

#define DEV __device__ __forceinline__

DEV float gelu_exact(float x) {
    return 0.5f * x * (1.0f + erff(x * 0.70710678118654752f));
}

// ---------------- K1: adjacency bitmask ----------------
__global__ __launch_bounds__(512)
void mask_kernel(const float* __restrict__ emb,
                 unsigned long long* __restrict__ maskw) {
    const int i = blockIdx.x;
    const int j = threadIdx.x;
    float ei[8], ej[8];
    float si = 0.f, sj = 0.f;
#pragma unroll
    for (int e = 0; e < 8; ++e) { ei[e] = emb[i * 8 + e]; si += ei[e] * ei[e]; }
    const int jj = (j < 500) ? j : 0;
#pragma unroll
    for (int e = 0; e < 8; ++e) { ej[e] = emb[jj * 8 + e]; sj += ej[e] * ej[e]; }
    const float ri = 1.0f / sqrtf(si);
    const float rj = 1.0f / sqrtf(sj);
    float dot = 0.f;
#pragma unroll
    for (int e = 0; e < 8; ++e) dot += (ei[e] * ri) * (ej[e] * rj);
    const bool pred = (j < 500) && (dot > 0.5f);
    unsigned long long m = __ballot(pred);
    if ((threadIdx.x & 63) == 0) maskw[i * 8 + (threadIdx.x >> 6)] = m;
}

// ---------------- K2/K3: per-layer GAT ----------------
// grid = 96 graphs * 4 heads = 384 blocks, block = 512 threads (1 row/thread).
template <int C, int OUTS, bool PROJ, bool GELU_OUT>
__global__ __launch_bounds__(512)
void gat_kernel(const float* __restrict__ in,
                const float* __restrict__ pw,   // [3,8] (PROJ only)
                const float* __restrict__ pb,   // [8]
                const float* __restrict__ W,    // [8,4,C]
                const float* __restrict__ asrc, // [4,C]
                const float* __restrict__ adst, // [4,C]
                const float* __restrict__ bias, // [4*C]
                const unsigned long long* __restrict__ maskw, // [500][8]
                float* __restrict__ out) {      // [96,500,OUTS]
    using Vec = std::conditional_t<C == 2, float2, float4>;
    const int b = blockIdx.x >> 2;
    const int head = blockIdx.x & 3;
    const int tid = threadIdx.x;
    __shared__ float xh[500 * 9];   // stride 9 (odd) for scalar re-reads
    __shared__ Vec h1[500];         // vector fragment -> single ds_read_b64/b128
    __shared__ float ssrc[500];
    __shared__ float sdst[500];

    // A: stage input (optionally fused dense proj 3->8)
    if (tid < 500) {
        if constexpr (PROJ) {
            const float* xr = in + ((size_t)b * 500 + tid) * 3;
            const float x0 = xr[0], x1 = xr[1], x2 = xr[2];
#pragma unroll
            for (int e = 0; e < 8; ++e)
                xh[tid * 9 + e] = x0 * pw[e] + x1 * pw[8 + e] + x2 * pw[16 + e] + pb[e];
        } else {
            const float4* xr = (const float4*)(in + ((size_t)b * 500 + tid) * 8);
            const float4 v0 = xr[0], v1 = xr[1];
            xh[tid * 9 + 0] = v0.x; xh[tid * 9 + 1] = v0.y;
            xh[tid * 9 + 2] = v0.z; xh[tid * 9 + 3] = v0.w;
            xh[tid * 9 + 4] = v1.x; xh[tid * 9 + 5] = v1.y;
            xh[tid * 9 + 6] = v1.z; xh[tid * 9 + 7] = v1.w;
        }
    }
    __syncthreads();

    // B: per-head projection + attention logits (weights wave-uniform)
    if (tid < 500) {
        float xv[8];
#pragma unroll
        for (int e = 0; e < 8; ++e) xv[e] = xh[tid * 9 + e];
        float acc[C];
#pragma unroll
        for (int c = 0; c < C; ++c) acc[c] = 0.f;
#pragma unroll
        for (int e = 0; e < 8; ++e) {
            const float xe = xv[e];
#pragma unroll
            for (int c = 0; c < C; ++c) acc[c] += xe * W[(e * 4 + head) * C + c];
        }
        float ss = 0.f, sd = 0.f;
#pragma unroll
        for (int c = 0; c < C; ++c) {
            ss += acc[c] * asrc[head * C + c];
            sd += acc[c] * adst[head * C + c];
        }
        Vec hv;
        if constexpr (C == 2) { hv.x = acc[0]; hv.y = acc[1]; }
        else { hv.x = acc[0]; hv.y = acc[1]; hv.z = acc[2]; hv.w = acc[3]; }
        h1[tid] = hv;
        ssrc[tid] = ss;
        sdst[tid] = sd;
    }
    __syncthreads();

    // C: masked rank-1 softmax aggregation (bit-scan over sparse neighbors)
    if (tid < 500) {
        const int i = tid;
        const float dd = sdst[i];
        float num[C];
#pragma unroll
        for (int c = 0; c < C; ++c) num[c] = 0.f;
        float den = 0.f;
#pragma unroll 1
        for (int wi = 0; wi < 8; ++wi) {
            unsigned long long m = maskw[i * 8 + wi];
            while (m) {
                const int bit = __ffsll(m) - 1;
                m &= (m - 1);
                const int j = wi * 64 + bit;
                float e = dd + ssrc[j];
                e = (e > 0.f) ? e : 0.2f * e;
                const float w = __expf(e);
                den += w;
                const Vec hj = h1[j];
                if constexpr (C == 2) { num[0] += w * hj.x; num[1] += w * hj.y; }
                else { num[0] += w * hj.x; num[1] += w * hj.y;
                       num[2] += w * hj.z; num[3] += w * hj.w; }
            }
        }
        const float inv = 1.0f / den;  // diag self-loop guarantees den > 0
        float* orow = out + ((size_t)b * 500 + i) * OUTS + head * C;
#pragma unroll
        for (int c = 0; c < C; ++c) {
            float v = num[c] * inv + bias[head * C + c];
            if constexpr (GELU_OUT) v = gelu_exact(v);
            orow[c] = v;
        }
    }
}

// ---------------- K4: transformer + pool + regressor ----------------
// grid = 2000 sequences, block = 64 threads (1 wave).
// All LDS row reads are float4 (ds_read_b128); weight columns hoisted to VGPRs.
__global__ __launch_bounds__(64)
void transformer_kernel(const float* __restrict__ tin,  // [2000,24,16]
                        const float* __restrict__ wq, const float* __restrict__ bq,
                        const float* __restrict__ wk, const float* __restrict__ bk,
                        const float* __restrict__ wv, const float* __restrict__ bv,
                        const float* __restrict__ wo, const float* __restrict__ bo,
                        const float* __restrict__ ln1g, const float* __restrict__ ln1b,
                        const float* __restrict__ ln2g, const float* __restrict__ ln2b,
                        const float* __restrict__ fw1, const float* __restrict__ fb1,
                        const float* __restrict__ fw2, const float* __restrict__ fb2,
                        const float* __restrict__ rw1, const float* __restrict__ rb1,
                        const float* __restrict__ rw2, const float* __restrict__ rb2,
                        float* __restrict__ outp) {
    const int r = blockIdx.x;
    const int lane = threadIdx.x;
    const int d = lane & 15;
    const int srow = lane >> 4;   // 0..3
    const int f = lane & 31;      // FFN1 column
    const int s2 = lane >> 5;     // 0..1
    __shared__ float t0[24][16], qs[24][16], ks[24][16], vs[24][16];
    __shared__ float os[24][16], t1[24][16], hid[24][32], pooled[16];

    // stage t0 (float4) + hoist QKV weight columns (global, overlaps staging)
    const float4* row4 = (const float4*)(tin + (size_t)r * 384);
    float4* t04 = (float4*)&t0[0][0];
    for (int idx = lane; idx < 96; idx += 64) t04[idx] = row4[idx];
    float wqc[16], wkc[16], wvc[16];
#pragma unroll
    for (int e = 0; e < 16; ++e) {
        wqc[e] = wq[e * 16 + d];
        wkc[e] = wk[e * 16 + d];
        wvc[e] = wv[e * 16 + d];
    }
    const float bqv = bq[d], bkv = bk[d], bvv = bv[d];
    __syncthreads();

    // QKV
#pragma unroll
    for (int it = 0; it < 6; ++it) {
        const int s = it * 4 + srow;
        const float4 r0 = *(const float4*)&t0[s][0];
        const float4 r1 = *(const float4*)&t0[s][4];
        const float4 r2 = *(const float4*)&t0[s][8];
        const float4 r3 = *(const float4*)&t0[s][12];
        const float te[16] = {r0.x, r0.y, r0.z, r0.w, r1.x, r1.y, r1.z, r1.w,
                              r2.x, r2.y, r2.z, r2.w, r3.x, r3.y, r3.z, r3.w};
        float aq = bqv, ak = bkv, av = bvv;
#pragma unroll
        for (int e = 0; e < 16; ++e) {
            aq += te[e] * wqc[e];
            ak += te[e] * wkc[e];
            av += te[e] * wvc[e];
        }
        qs[s][d] = aq; ks[s][d] = ak; vs[s][d] = av;
    }
    __syncthreads();

    // attention: lane = h*24 + s for lane < 48 (float4 K/V reads)
    if (lane < 48) {
        const int h = lane / 24, s = lane % 24;
        const float4 q0 = *(const float4*)&qs[s][h * 8];
        const float4 q1 = *(const float4*)&qs[s][h * 8 + 4];
        float sc[24];
        float mx = -1e30f;
#pragma unroll
        for (int t = 0; t < 24; ++t) {
            const float4 k0 = *(const float4*)&ks[t][h * 8];
            const float4 k1 = *(const float4*)&ks[t][h * 8 + 4];
            float a = q0.x * k0.x + q0.y * k0.y + q0.z * k0.z + q0.w * k0.w +
                      q1.x * k1.x + q1.y * k1.y + q1.z * k1.z + q1.w * k1.w;
            a *= 0.35355339059327373f;  // 1/sqrt(8)
            sc[t] = a;
            mx = fmaxf(mx, a);
        }
        float sum = 0.f;
#pragma unroll
        for (int t = 0; t < 24; ++t) { sc[t] = __expf(sc[t] - mx); sum += sc[t]; }
        const float inv = 1.0f / sum;
        float o0x = 0.f, o0y = 0.f, o0z = 0.f, o0w = 0.f;
        float o1x = 0.f, o1y = 0.f, o1z = 0.f, o1w = 0.f;
#pragma unroll
        for (int t = 0; t < 24; ++t) {
            const float4 v0 = *(const float4*)&vs[t][h * 8];
            const float4 v1 = *(const float4*)&vs[t][h * 8 + 4];
            const float w = sc[t];
            o0x += w * v0.x; o0y += w * v0.y; o0z += w * v0.z; o0w += w * v0.w;
            o1x += w * v1.x; o1y += w * v1.y; o1z += w * v1.z; o1w += w * v1.w;
        }
        float4 ov0 = {o0x * inv, o0y * inv, o0z * inv, o0w * inv};
        float4 ov1 = {o1x * inv, o1y * inv, o1z * inv, o1w * inv};
        *(float4*)&os[s][h * 8] = ov0;
        *(float4*)&os[s][h * 8 + 4] = ov1;
    }
    // hoist out-proj weights while attention lanes work
    float woc[16];
#pragma unroll
    for (int hd = 0; hd < 16; ++hd) woc[hd] = wo[hd * 16 + d];
    const float bov = bo[d];
    const float g1v = ln1g[d], be1v = ln1b[d];
    __syncthreads();

    // out-proj + residual + LN1 (shuffle LN within 16-lane groups)
#pragma unroll
    for (int it = 0; it < 6; ++it) {
        const int s = it * 4 + srow;
        const float4 r0 = *(const float4*)&os[s][0];
        const float4 r1 = *(const float4*)&os[s][4];
        const float4 r2 = *(const float4*)&os[s][8];
        const float4 r3 = *(const float4*)&os[s][12];
        const float oe[16] = {r0.x, r0.y, r0.z, r0.w, r1.x, r1.y, r1.z, r1.w,
                              r2.x, r2.y, r2.z, r2.w, r3.x, r3.y, r3.z, r3.w};
        float a = bov;
#pragma unroll
        for (int hd = 0; hd < 16; ++hd) a += oe[hd] * woc[hd];
        float xv = t0[s][d] + a;
        float sum = xv;
        sum += __shfl_xor(sum, 1); sum += __shfl_xor(sum, 2);
        sum += __shfl_xor(sum, 4); sum += __shfl_xor(sum, 8);
        const float mean = sum * 0.0625f;
        const float df = xv - mean;
        float v2 = df * df;
        v2 += __shfl_xor(v2, 1); v2 += __shfl_xor(v2, 2);
        v2 += __shfl_xor(v2, 4); v2 += __shfl_xor(v2, 8);
        const float var = v2 * 0.0625f;
        t1[s][d] = df * rsqrtf(var + 1e-3f) * g1v + be1v;
    }
    // hoist FFN1 weights
    float f1c[16];
#pragma unroll
    for (int e = 0; e < 16; ++e) f1c[e] = fw1[e * 32 + f];
    const float fb1v = fb1[f];
    __syncthreads();

    // FFN hidden [24][32]: lane column f fixed, rows s = it*2 + s2
#pragma unroll
    for (int it = 0; it < 12; ++it) {
        const int s = it * 2 + s2;
        const float4 r0 = *(const float4*)&t1[s][0];
        const float4 r1 = *(const float4*)&t1[s][4];
        const float4 r2 = *(const float4*)&t1[s][8];
        const float4 r3 = *(const float4*)&t1[s][12];
        const float te[16] = {r0.x, r0.y, r0.z, r0.w, r1.x, r1.y, r1.z, r1.w,
                              r2.x, r2.y, r2.z, r2.w, r3.x, r3.y, r3.z, r3.w};
        float a = fb1v;
#pragma unroll
        for (int e = 0; e < 16; ++e) a += te[e] * f1c[e];
        hid[s][f] = gelu_exact(a);
    }
    // hoist FFN2 weights
    float f2c[32];
#pragma unroll
    for (int ff = 0; ff < 32; ++ff) f2c[ff] = fw2[ff * 16 + d];
    const float fb2v = fb2[d];
    const float g2v = ln2g[d], be2v = ln2b[d];
    __syncthreads();

    // FFN out + residual + LN2 (shuffle LN) + fused mean-pool accumulate
    float pacc = 0.f;
#pragma unroll
    for (int it = 0; it < 6; ++it) {
        const int s = it * 4 + srow;
        float he[32];
#pragma unroll
        for (int q8 = 0; q8 < 8; ++q8) {
            const float4 rv = *(const float4*)&hid[s][q8 * 4];
            he[q8 * 4 + 0] = rv.x; he[q8 * 4 + 1] = rv.y;
            he[q8 * 4 + 2] = rv.z; he[q8 * 4 + 3] = rv.w;
        }
        float a = fb2v;
#pragma unroll
        for (int ff = 0; ff < 32; ++ff) a += he[ff] * f2c[ff];
        float xv = t1[s][d] + a;
        float sum = xv;
        sum += __shfl_xor(sum, 1); sum += __shfl_xor(sum, 2);
        sum += __shfl_xor(sum, 4); sum += __shfl_xor(sum, 8);
        const float mean = sum * 0.0625f;
        const float df = xv - mean;
        float v2 = df * df;
        v2 += __shfl_xor(v2, 1); v2 += __shfl_xor(v2, 2);
        v2 += __shfl_xor(v2, 4); v2 += __shfl_xor(v2, 8);
        const float var = v2 * 0.0625f;
        pacc += df * rsqrtf(var + 1e-3f) * g2v + be2v;
    }
    pacc += __shfl_xor(pacc, 16);
    pacc += __shfl_xor(pacc, 32);
    if (lane < 16) pooled[lane] = pacc * (1.0f / 24.0f);
    __syncthreads();

    // regressor: gelu(pooled @ rw1 + rb1) @ rw2 + rb2
    float partial = 0.f;
    if (lane < 16) {
        float a = rb1[lane];
#pragma unroll
        for (int e = 0; e < 16; ++e) a += pooled[e] * rw1[e * 16 + lane];
        partial = gelu_exact(a) * rw2[lane];
    }
    partial += __shfl_xor(partial, 8);
    partial += __shfl_xor(partial, 4);
    partial += __shfl_xor(partial, 2);
    partial += __shfl_xor(partial, 1);
    if (lane == 0) outp[r] = partial + rb2[0];
}

extern "C" void kernel_launch(void* const* d_in, const int* in_sizes, int n_in,
                              void* d_out, int out_size, void* d_ws, size_t ws_size,
                              hipStream_t stream) {
    const float* x      = (const float*)d_in[0];
    const float* emb    = (const float*)d_in[1];
    const float* proj_w = (const float*)d_in[2];
    const float* proj_b = (const float*)d_in[3];
    const float* g1_w   = (const float*)d_in[4];
    const float* g1_as  = (const float*)d_in[5];
    const float* g1_ad  = (const float*)d_in[6];
    const float* g1_b   = (const float*)d_in[7];
    const float* g2_w   = (const float*)d_in[8];
    const float* g2_as  = (const float*)d_in[9];
    const float* g2_ad  = (const float*)d_in[10];
    const float* g2_b   = (const float*)d_in[11];
    const float* wq = (const float*)d_in[12];
    const float* bq = (const float*)d_in[13];
    const float* wk = (const float*)d_in[14];
    const float* bk = (const float*)d_in[15];
    const float* wv = (const float*)d_in[16];
    const float* bv = (const float*)d_in[17];
    const float* wo = (const float*)d_in[18];
    const float* bo = (const float*)d_in[19];
    const float* ln1g = (const float*)d_in[20];
    const float* ln1b = (const float*)d_in[21];
    const float* ln2g = (const float*)d_in[22];
    const float* ln2b = (const float*)d_in[23];
    const float* fw1 = (const float*)d_in[24];
    const float* fb1 = (const float*)d_in[25];
    const float* fw2 = (const float*)d_in[26];
    const float* fb2 = (const float*)d_in[27];
    const float* rw1 = (const float*)d_in[28];
    const float* rb1 = (const float*)d_in[29];
    const float* rw2 = (const float*)d_in[30];
    const float* rb2 = (const float*)d_in[31];

    unsigned long long* maskw = (unsigned long long*)d_ws;   // 32000 B (pad to 32768)
    float* h_g1  = (float*)((char*)d_ws + 32768);            // 96*500*8*4  = 1,536,000 B
    float* t_buf = (float*)((char*)d_ws + 32768 + 1536000);  // 96*500*16*4 = 3,072,000 B

    mask_kernel<<<500, 512, 0, stream>>>(emb, maskw);
    gat_kernel<2, 8, true, true><<<384, 512, 0, stream>>>(
        x, proj_w, proj_b, g1_w, g1_as, g1_ad, g1_b, maskw, h_g1);
    gat_kernel<4, 16, false, false><<<384, 512, 0, stream>>>(
        h_g1, nullptr, nullptr, g2_w, g2_as, g2_ad, g2_b, maskw, t_buf);
    transformer_kernel<<<2000, 64, 0, stream>>>(
        t_buf, wq, bq, wk, bk, wv, bv, wo, bo, ln1g, ln1b, ln2g, ln2b,
        fw1, fb1, fw2, fb2, rw1, rb1, rw2, rb2, (float*)d_out);
}